// Round 11
// baseline (295.825 us; speedup 1.0000x reference)
//
#include <hip/hip_runtime.h>
#include <math.h>

#define N_NODES 100000
#define N_EDGES 1600000
#define DIM 64
#define N_LAYERS 6
#define N_COEF 8
#define NSTEP 18              // K=576 / 32
#define NTILE 64              // nodes per kan block-tile (4 m-tiles)
#define KAN_BLOCKS (N_NODES / NTILE)  // 1563 (last tile partial-safe: 100000/64=1562.5 -> pad)

// prep kernel region split (256-thread blocks)
#define WCF_BLOCKS 108        // 27648 threads
#define RP_BLOCKS  391        // 100096 threads
#define CONV_BLOCKS 6250      // 1.6M threads (4 elems each)

typedef _Float16 f16x8 __attribute__((ext_vector_type(8)));
typedef _Float16 f16x4 __attribute__((ext_vector_type(4)));
typedef float f32x4 __attribute__((ext_vector_type(4)));

__device__ __forceinline__ unsigned f16u(float v) {
    return (unsigned)__builtin_bit_cast(unsigned short, (_Float16)v);
}

// ---------------------------------------------------------------------------
// prep: (a) weight fold to MFMA B-fragments, (b) row_ptr binary search,
// (c) x f32->f16. Region-split by blockIdx.
// ---------------------------------------------------------------------------
__global__ __launch_bounds__(256) void prep(const float* __restrict__ bw,
                                            const float* __restrict__ sw,
                                            const float* __restrict__ ss,
                                            uint4* __restrict__ wcf,
                                            const int* __restrict__ erow,
                                            int* __restrict__ rp,
                                            const float* __restrict__ x,
                                            _Float16* __restrict__ H0) {
    int bid = blockIdx.x;
    if (bid < WCF_BLOCKS) {
        int idx = bid * 256 + threadIdx.x;   // < 27648 = 6*18*4*64
        int lane = idx & 63;
        int nt   = (idx >> 6) & 3;
        int s    = (idx >> 8) % NSTEP;
        int l    = idx / (64 * 4 * NSTEP);
        int o = nt * 16 + (lane & 15);
        unsigned short h[8];
#pragma unroll
        for (int j = 0; j < 8; ++j) {
            int k = s * 32 + ((lane >> 4) << 3) + j;
            int d = k / 9;
            int r = k - d * 9;
            float v;
            if (r == 0) v = bw[(l * DIM + o) * DIM + d];
            else        v = sw[((l * DIM + o) * DIM + d) * N_COEF + (r - 1)] *
                            ss[(l * DIM + o) * DIM + d];
            h[j] = __builtin_bit_cast(unsigned short, (_Float16)v);
        }
        uint4 uh;
        uh.x = (unsigned)h[0] | ((unsigned)h[1] << 16);
        uh.y = (unsigned)h[2] | ((unsigned)h[3] << 16);
        uh.z = (unsigned)h[4] | ((unsigned)h[5] << 16);
        uh.w = (unsigned)h[6] | ((unsigned)h[7] << 16);
        wcf[((l * NSTEP + s) * 4 + nt) * 64 + lane] = uh;
    } else if (bid < WCF_BLOCKS + RP_BLOCKS) {
        int i = (bid - WCF_BLOCKS) * 256 + threadIdx.x;
        if (i > N_NODES) return;
        if (i == N_NODES) { rp[i] = N_EDGES; return; }
        int a = 0, b = N_EDGES;
        while (a < b) { int m = (a + b) >> 1; if (erow[m] < i) a = m + 1; else b = m; }
        rp[i] = a;
    } else {
        int i = (bid - WCF_BLOCKS - RP_BLOCKS) * 256 + threadIdx.x;  // < 1.6M
        float4 v = *(const float4*)(x + (size_t)i * 4);
        f16x4 h = { (_Float16)v.x, (_Float16)v.y, (_Float16)v.z, (_Float16)v.w };
        *(f16x4*)(H0 + (size_t)i * 4) = h;
    }
}

// ---------------------------------------------------------------------------
// SpMM, quarter-wide, f16 rows, 16-edge batches (4 gathers in flight) —
// R9 form, the best of the three measured spmm variants (45-46 us; gather
// memory path is the floor, not instructions).
// ---------------------------------------------------------------------------
#define META16(C, V, BASE)                                              \
    _Pragma("unroll")                                                   \
    for (int i_ = 0; i_ < 4; ++i_) {                                    \
        int e_ = (BASE) + 4 * i_ + q;                                   \
        if (e_ < end) { C[i_] = ecol[e_]; V[i_] = ev[e_]; }             \
        else          { C[i_] = 0;        V[i_] = 0.f; }                \
    }

__global__ __launch_bounds__(256) void spmm_kernel(const int* __restrict__ rp,
                                                   const int* __restrict__ ecol,
                                                   const float* __restrict__ ev,
                                                   const _Float16* __restrict__ x,
                                                   _Float16* __restrict__ y) {
    int wid = (blockIdx.x * blockDim.x + threadIdx.x) >> 6;
    int lane = threadIdx.x & 63;
    if (wid >= N_NODES) return;
    int q = lane >> 4;        // edge slot within gather round
    int c16 = lane & 15;      // 8B chunk within the 128B row
    int e0 = rp[wid], end = rp[wid + 1];

    float4 acc = {0.f, 0.f, 0.f, 0.f};
    int ca[4]; float va[4];
    int cb[4]; float vb[4];
    META16(ca, va, e0)

    for (int eb = e0; eb < end; eb += 16) {
        META16(cb, vb, eb + 16)
        f16x4 g0 = *(const f16x4*)&x[((unsigned)ca[0] << 6) + c16 * 4];
        f16x4 g1 = *(const f16x4*)&x[((unsigned)ca[1] << 6) + c16 * 4];
        f16x4 g2 = *(const f16x4*)&x[((unsigned)ca[2] << 6) + c16 * 4];
        f16x4 g3 = *(const f16x4*)&x[((unsigned)ca[3] << 6) + c16 * 4];
        acc.x += va[0] * (float)g0[0]; acc.y += va[0] * (float)g0[1];
        acc.z += va[0] * (float)g0[2]; acc.w += va[0] * (float)g0[3];
        acc.x += va[1] * (float)g1[0]; acc.y += va[1] * (float)g1[1];
        acc.z += va[1] * (float)g1[2]; acc.w += va[1] * (float)g1[3];
        acc.x += va[2] * (float)g2[0]; acc.y += va[2] * (float)g2[1];
        acc.z += va[2] * (float)g2[2]; acc.w += va[2] * (float)g2[3];
        acc.x += va[3] * (float)g3[0]; acc.y += va[3] * (float)g3[1];
        acc.z += va[3] * (float)g3[2]; acc.w += va[3] * (float)g3[3];
#pragma unroll
        for (int i_ = 0; i_ < 4; ++i_) { ca[i_] = cb[i_]; va[i_] = vb[i_]; }
    }

    acc.x += __shfl_xor(acc.x, 16); acc.y += __shfl_xor(acc.y, 16);
    acc.z += __shfl_xor(acc.z, 16); acc.w += __shfl_xor(acc.w, 16);
    acc.x += __shfl_xor(acc.x, 32); acc.y += __shfl_xor(acc.y, 32);
    acc.z += __shfl_xor(acc.z, 32); acc.w += __shfl_xor(acc.w, 32);

    if (lane < 16) {
        f16x4 h = { (_Float16)acc.x, (_Float16)acc.y, (_Float16)acc.z, (_Float16)acc.w };
        *(f16x4*)&y[(size_t)wid * DIM + c16 * 4] = h;
    }
}

// ---------------------------------------------------------------------------
// Spline window: 4 nonzero cubic B-spline bases as f16 pairs, positioned into
// an 8-slot (128-bit) window via 64-bit shifts.
// ---------------------------------------------------------------------------
__device__ __forceinline__ void spline_window(float xv, unsigned long long& lo,
                                              unsigned long long& hi) {
    float t = xv * 2.5f + 5.5f;        // grid units on extended grid, h=0.4
    float fl = floorf(t);
    float u = t - fl;
    int c = (int)fl;
    bool valid = (t >= 0.f) && (t < 11.f);
    float u2 = u * u, u3 = u2 * u, um = 1.f - u;
    const float k6 = 1.f / 6.f;
    float N0 = um * um * um * k6;
    float N1 = (3.f * u3 - 6.f * u2 + 4.f) * k6;
    float N2 = (-3.f * u3 + 3.f * u2 + 3.f * u + 1.f) * k6;
    float N3 = u3 * k6;
    if (!valid) { N0 = 0.f; N1 = 0.f; N2 = 0.f; N3 = 0.f; }
    unsigned n01 = f16u(N0) | (f16u(N1) << 16);
    unsigned n23 = f16u(N2) | (f16u(N3) << 16);
    unsigned long long big = (unsigned long long)n01 | ((unsigned long long)n23 << 32);
    int qb = c - 3;
    qb = qb < -3 ? -3 : (qb > 7 ? 7 : qb);   // invalid => big==0, clamp keeps shifts legal
    int sh = qb * 16;
    lo = 0; hi = 0;
    if (sh >= 0) {
        if (sh < 64) { lo = big << sh; hi = (big >> 1) >> (63 - sh); }  // N3>=0 => bit63==0
        else         { hi = big << (sh - 64); }
    } else {
        lo = big >> (-sh);
    }
}

// Feature pair -> 9 packed dwords into octave-swizzled LDS.
__device__ __forceinline__ void feat_pair(char* lds, int lbase, int Xsw, int d,
                                          float xe, float xo) {
    float se_f = xe * __builtin_amdgcn_rcpf(1.f + __expf(-xe));
    float so_f = xo * __builtin_amdgcn_rcpf(1.f + __expf(-xo));
    unsigned se = f16u(se_f), so = f16u(so_f);

    unsigned long long loE, hiE, loO, hiO;
    spline_window(xe, loE, hiE);
    spline_window(xo, loO, hiO);

    unsigned wv[9];
    wv[0] = se | ((unsigned)loE << 16);
    wv[1] = (unsigned)(loE >> 16);
    wv[2] = (unsigned)(loE >> 48) | ((unsigned)hiE << 16);
    wv[3] = (unsigned)(hiE >> 16);
    wv[4] = (unsigned)(hiE >> 48) | (so << 16);
    wv[5] = (unsigned)loO;
    wv[6] = (unsigned)(loO >> 32);
    wv[7] = (unsigned)hiO;
    wv[8] = (unsigned)(hiO >> 32);

    int base = lbase + 18 * d;   // d even -> 4B aligned
#pragma unroll
    for (int j = 0; j < 9; ++j)
        *(unsigned*)(&lds[(base + 4 * j) ^ Xsw]) = wv[j];
}

// ---------------------------------------------------------------------------
// KANLinear via f16 MFMA (16x16x32). NTILE=64, 4 waves: wave w = o-tile w
// across FOUR m-tiles -> each streamed weight fragment is reused 4x (weight
// L2 traffic 225 -> 112 MB/layer), barriers per node halve, 4 independent
// MFMA chains give in-wave latency overlap. LDS 73.7 KB -> 2 blocks/CU.
// Default launch bounds (R6 lesson). f16 in, f16 or f32 out. In-place safe.
// Handles the partial last tile (100000 = 1562*64 + 32) via node clamping.
// ---------------------------------------------------------------------------
template<int F32OUT>
__global__ __launch_bounds__(256) void kan_mfma(const _Float16* __restrict__ xin,
                                                const uint4* __restrict__ wl,
                                                void* __restrict__ outp) {
    __shared__ alignas(16) char lds[NTILE * 1152];  // 73728 B

    int tid = threadIdx.x;
    int lane = tid & 63;
    int w = tid >> 6;
    int node0 = blockIdx.x * NTILE;

    // ---- feature phase: fn = node (0..63), fq = quad slot (0..3) ----
    int fn = tid >> 2;
    int fq = tid & 3;
    bool live = (node0 + fn) < N_NODES;
    int Xsw = (fn & 7) << 4;
    int lbase = fn * 1152;
    if (live) {
        const _Float16* xr_ = &xin[(size_t)(node0 + fn) * DIM + fq * 4];
#pragma unroll
        for (int i = 0; i < 4; ++i) {
            f16x4 h = *(const f16x4*)(xr_ + i * 16);
            int d0 = fq * 4 + i * 16;
            feat_pair(lds, lbase, Xsw, d0,     (float)h[0], (float)h[1]);
            feat_pair(lds, lbase, Xsw, d0 + 2, (float)h[2], (float)h[3]);
        }
    }
    __syncthreads();

    // ---- MFMA phase: wave w = o-tile w, four m-tiles ----
    int row = lane & 15, kg = lane >> 4;
    int xr = (row & 7) << 4;
    int rb0 = (0 * 16 + row) * 1152;
    int rb1 = (1 * 16 + row) * 1152;
    int rb2 = (2 * 16 + row) * 1152;
    int rb3 = (3 * 16 + row) * 1152;

    f32x4 acc0 = {0.f, 0.f, 0.f, 0.f};
    f32x4 acc1 = {0.f, 0.f, 0.f, 0.f};
    f32x4 acc2 = {0.f, 0.f, 0.f, 0.f};
    f32x4 acc3 = {0.f, 0.f, 0.f, 0.f};
#pragma unroll
    for (int s = 0; s < NSTEP; ++s) {
        f16x8 bh = __builtin_bit_cast(f16x8, wl[(s * 4 + w) * 64 + lane]);
        int pofs = ((s * 4 + kg) << 4) ^ xr;
        f16x8 a0 = *(const f16x8*)(&lds[rb0 + pofs]);
        f16x8 a1 = *(const f16x8*)(&lds[rb1 + pofs]);
        f16x8 a2 = *(const f16x8*)(&lds[rb2 + pofs]);
        f16x8 a3 = *(const f16x8*)(&lds[rb3 + pofs]);
        acc0 = __builtin_amdgcn_mfma_f32_16x16x32_f16(a0, bh, acc0, 0, 0, 0);
        acc1 = __builtin_amdgcn_mfma_f32_16x16x32_f16(a1, bh, acc1, 0, 0, 0);
        acc2 = __builtin_amdgcn_mfma_f32_16x16x32_f16(a2, bh, acc2, 0, 0, 0);
        acc3 = __builtin_amdgcn_mfma_f32_16x16x32_f16(a3, bh, acc3, 0, 0, 0);
    }

    // ---- store: C layout col=lane&15 (o), row=(lane>>4)*4+r (node) ----
    int o = w * 16 + row;
    int rbase = kg * 4;
#pragma unroll
    for (int m = 0; m < 4; ++m) {
        f32x4 acc = m == 0 ? acc0 : m == 1 ? acc1 : m == 2 ? acc2 : acc3;
        int nb = node0 + m * 16 + rbase;
        if (nb >= N_NODES) continue;
        if (F32OUT) {
            float* out = (float*)outp;
#pragma unroll
            for (int r = 0; r < 4; ++r)
                out[(size_t)(nb + r) * DIM + o] = acc[r];
        } else {
            _Float16* out = (_Float16*)outp;
#pragma unroll
            for (int r = 0; r < 4; ++r)
                out[(size_t)(nb + r) * DIM + o] = (_Float16)acc[r];
        }
    }
}

extern "C" void kernel_launch(void* const* d_in, const int* in_sizes, int n_in,
                              void* d_out, int out_size, void* d_ws, size_t ws_size,
                              hipStream_t stream) {
    const float* x     = (const float*)d_in[0];
    const float* eval_ = (const float*)d_in[1];
    const float* bw    = (const float*)d_in[2];
    const float* sw    = (const float*)d_in[3];
    const float* ss    = (const float*)d_in[4];
    const int*   erow  = (const int*)d_in[5];
    const int*   ecol  = (const int*)d_in[6];
    float* out = (float*)d_out;

    // ws layout: [H0: 12.8MB f16][H1: 12.8MB f16][wcf: 442368B][rp: 400004B]
    const size_t HB = (size_t)N_NODES * DIM * sizeof(_Float16);
    _Float16* H0 = (_Float16*)d_ws;
    _Float16* H1 = (_Float16*)((char*)d_ws + HB);
    uint4* wcf = (uint4*)((char*)d_ws + 2 * HB);
    int*   rp  = (int*)((char*)d_ws + 2 * HB + 442368);

    const size_t WL = (size_t)NSTEP * 4 * 64;  // uint4 per layer
    const int KB = (N_NODES + NTILE - 1) / NTILE;  // 1563

    prep<<<WCF_BLOCKS + RP_BLOCKS + CONV_BLOCKS, 256, 0, stream>>>(
        bw, sw, ss, wcf, erow, rp, x, H0);

    const int SPMM_BLOCKS = N_NODES / 4;

    spmm_kernel<<<SPMM_BLOCKS, 256, 0, stream>>>(rp, ecol, eval_, H0, H1);
    kan_mfma<0><<<KB, 256, 0, stream>>>(H1, wcf + 0 * WL, H1);  // in place
    kan_mfma<0><<<KB, 256, 0, stream>>>(H1, wcf + 1 * WL, H0);

    spmm_kernel<<<SPMM_BLOCKS, 256, 0, stream>>>(rp, ecol, eval_, H0, H1);
    kan_mfma<0><<<KB, 256, 0, stream>>>(H1, wcf + 2 * WL, H1);  // in place
    kan_mfma<0><<<KB, 256, 0, stream>>>(H1, wcf + 3 * WL, H0);

    spmm_kernel<<<SPMM_BLOCKS, 256, 0, stream>>>(rp, ecol, eval_, H0, H1);
    kan_mfma<0><<<KB, 256, 0, stream>>>(H1, wcf + 4 * WL, H1);  // in place
    kan_mfma<1><<<KB, 256, 0, stream>>>(H1, wcf + 5 * WL, out);
}

// Round 13
// 240.988 us; speedup vs baseline: 1.2275x; 1.2275x over previous
//
#include <hip/hip_runtime.h>
#include <math.h>

#define N_NODES 100000
#define N_EDGES 1600000
#define DIM 64
#define N_LAYERS 6
#define N_COEF 8
#define NSTEP 18              // K=576 / 32
#define NTILE 32              // nodes per kan block-tile
#define KAN_BLOCKS (N_NODES / NTILE)  // 3125
#define C1S 68                // c1 row stride in f16 (64 + 4 pad)

// prep kernel region split (256-thread blocks)
#define WCF_BLOCKS 108        // 27648 threads
#define RP_BLOCKS  391        // 100096 threads
#define CONV_BLOCKS 6250      // 1.6M threads (4 elems each)

typedef _Float16 f16x8 __attribute__((ext_vector_type(8)));
typedef _Float16 f16x4 __attribute__((ext_vector_type(4)));
typedef float f32x4 __attribute__((ext_vector_type(4)));

__device__ __forceinline__ unsigned f16u(float v) {
    return (unsigned)__builtin_bit_cast(unsigned short, (_Float16)v);
}

// ---------------------------------------------------------------------------
// prep: (a) weight fold to MFMA B-fragments, (b) row_ptr binary search,
// (c) x f32->f16. Region-split by blockIdx.
// ---------------------------------------------------------------------------
__global__ __launch_bounds__(256) void prep(const float* __restrict__ bw,
                                            const float* __restrict__ sw,
                                            const float* __restrict__ ss,
                                            uint4* __restrict__ wcf,
                                            const int* __restrict__ erow,
                                            int* __restrict__ rp,
                                            const float* __restrict__ x,
                                            _Float16* __restrict__ H0) {
    int bid = blockIdx.x;
    if (bid < WCF_BLOCKS) {
        int idx = bid * 256 + threadIdx.x;   // < 27648 = 6*18*4*64
        int lane = idx & 63;
        int nt   = (idx >> 6) & 3;
        int s    = (idx >> 8) % NSTEP;
        int l    = idx / (64 * 4 * NSTEP);
        int o = nt * 16 + (lane & 15);
        unsigned short h[8];
#pragma unroll
        for (int j = 0; j < 8; ++j) {
            int k = s * 32 + ((lane >> 4) << 3) + j;
            int d = k / 9;
            int r = k - d * 9;
            float v;
            if (r == 0) v = bw[(l * DIM + o) * DIM + d];
            else        v = sw[((l * DIM + o) * DIM + d) * N_COEF + (r - 1)] *
                            ss[(l * DIM + o) * DIM + d];
            h[j] = __builtin_bit_cast(unsigned short, (_Float16)v);
        }
        uint4 uh;
        uh.x = (unsigned)h[0] | ((unsigned)h[1] << 16);
        uh.y = (unsigned)h[2] | ((unsigned)h[3] << 16);
        uh.z = (unsigned)h[4] | ((unsigned)h[5] << 16);
        uh.w = (unsigned)h[6] | ((unsigned)h[7] << 16);
        wcf[((l * NSTEP + s) * 4 + nt) * 64 + lane] = uh;
    } else if (bid < WCF_BLOCKS + RP_BLOCKS) {
        int i = (bid - WCF_BLOCKS) * 256 + threadIdx.x;
        if (i > N_NODES) return;
        if (i == N_NODES) { rp[i] = N_EDGES; return; }
        int a = 0, b = N_EDGES;
        while (a < b) { int m = (a + b) >> 1; if (erow[m] < i) a = m + 1; else b = m; }
        rp[i] = a;
    } else {
        int i = (bid - WCF_BLOCKS - RP_BLOCKS) * 256 + threadIdx.x;  // < 1.6M
        float4 v = *(const float4*)(x + (size_t)i * 4);
        f16x4 h = { (_Float16)v.x, (_Float16)v.y, (_Float16)v.z, (_Float16)v.w };
        *(f16x4*)(H0 + (size_t)i * 4) = h;
    }
}

// ---------------------------------------------------------------------------
// SpMM, quarter-wide, f16 rows, 16-edge batches (4 gathers in flight).
// R9/R11-proven version — four structural variants all land 45-49 us; the
// random-gather memory path is the floor. Do not touch.
// ---------------------------------------------------------------------------
#define META16(C, V, BASE)                                              \
    _Pragma("unroll")                                                   \
    for (int i_ = 0; i_ < 4; ++i_) {                                    \
        int e_ = (BASE) + 4 * i_ + q;                                   \
        if (e_ < end) { C[i_] = ecol[e_]; V[i_] = ev[e_]; }             \
        else          { C[i_] = 0;        V[i_] = 0.f; }                \
    }

__global__ __launch_bounds__(256) void spmm_kernel(const int* __restrict__ rp,
                                                   const int* __restrict__ ecol,
                                                   const float* __restrict__ ev,
                                                   const _Float16* __restrict__ x,
                                                   _Float16* __restrict__ y) {
    int wid = (blockIdx.x * blockDim.x + threadIdx.x) >> 6;
    int lane = threadIdx.x & 63;
    if (wid >= N_NODES) return;
    int q = lane >> 4;        // edge slot within gather round
    int c16 = lane & 15;      // 8B chunk within the 128B row
    int e0 = rp[wid], end = rp[wid + 1];

    float4 acc = {0.f, 0.f, 0.f, 0.f};
    int ca[4]; float va[4];
    int cb[4]; float vb[4];
    META16(ca, va, e0)

    for (int eb = e0; eb < end; eb += 16) {
        META16(cb, vb, eb + 16)
        f16x4 g0 = *(const f16x4*)&x[((unsigned)ca[0] << 6) + c16 * 4];
        f16x4 g1 = *(const f16x4*)&x[((unsigned)ca[1] << 6) + c16 * 4];
        f16x4 g2 = *(const f16x4*)&x[((unsigned)ca[2] << 6) + c16 * 4];
        f16x4 g3 = *(const f16x4*)&x[((unsigned)ca[3] << 6) + c16 * 4];
        acc.x += va[0] * (float)g0[0]; acc.y += va[0] * (float)g0[1];
        acc.z += va[0] * (float)g0[2]; acc.w += va[0] * (float)g0[3];
        acc.x += va[1] * (float)g1[0]; acc.y += va[1] * (float)g1[1];
        acc.z += va[1] * (float)g1[2]; acc.w += va[1] * (float)g1[3];
        acc.x += va[2] * (float)g2[0]; acc.y += va[2] * (float)g2[1];
        acc.z += va[2] * (float)g2[2]; acc.w += va[2] * (float)g2[3];
        acc.x += va[3] * (float)g3[0]; acc.y += va[3] * (float)g3[1];
        acc.z += va[3] * (float)g3[2]; acc.w += va[3] * (float)g3[3];
#pragma unroll
        for (int i_ = 0; i_ < 4; ++i_) { ca[i_] = cb[i_]; va[i_] = vb[i_]; }
    }

    acc.x += __shfl_xor(acc.x, 16); acc.y += __shfl_xor(acc.y, 16);
    acc.z += __shfl_xor(acc.z, 16); acc.w += __shfl_xor(acc.w, 16);
    acc.x += __shfl_xor(acc.x, 32); acc.y += __shfl_xor(acc.y, 32);
    acc.z += __shfl_xor(acc.z, 32); acc.w += __shfl_xor(acc.w, 32);

    if (lane < 16) {
        f16x4 h = { (_Float16)acc.x, (_Float16)acc.y, (_Float16)acc.z, (_Float16)acc.w };
        *(f16x4*)&y[(size_t)wid * DIM + c16 * 4] = h;
    }
}

// ---------------------------------------------------------------------------
// Spline window: 4 nonzero cubic B-spline bases as f16 pairs, positioned into
// an 8-slot (128-bit) window via 64-bit shifts.
// ---------------------------------------------------------------------------
__device__ __forceinline__ void spline_window(float xv, unsigned long long& lo,
                                              unsigned long long& hi) {
    float t = xv * 2.5f + 5.5f;        // grid units on extended grid, h=0.4
    float fl = floorf(t);
    float u = t - fl;
    int c = (int)fl;
    bool valid = (t >= 0.f) && (t < 11.f);
    float u2 = u * u, u3 = u2 * u, um = 1.f - u;
    const float k6 = 1.f / 6.f;
    float N0 = um * um * um * k6;
    float N1 = (3.f * u3 - 6.f * u2 + 4.f) * k6;
    float N2 = (-3.f * u3 + 3.f * u2 + 3.f * u + 1.f) * k6;
    float N3 = u3 * k6;
    if (!valid) { N0 = 0.f; N1 = 0.f; N2 = 0.f; N3 = 0.f; }
    unsigned n01 = f16u(N0) | (f16u(N1) << 16);
    unsigned n23 = f16u(N2) | (f16u(N3) << 16);
    unsigned long long big = (unsigned long long)n01 | ((unsigned long long)n23 << 32);
    int qb = c - 3;
    qb = qb < -3 ? -3 : (qb > 7 ? 7 : qb);   // invalid => big==0, clamp keeps shifts legal
    int sh = qb * 16;
    lo = 0; hi = 0;
    if (sh >= 0) {
        if (sh < 64) { lo = big << sh; hi = (big >> 1) >> (63 - sh); }  // N3>=0 => bit63==0
        else         { hi = big << (sh - 64); }
    } else {
        lo = big >> (-sh);
    }
}

// Feature pair -> 9 packed dwords into octave-swizzled LDS.
__device__ __forceinline__ void feat_pair(char* lds, int lbase, int Xsw, int d,
                                          float xe, float xo) {
    float se_f = xe * __builtin_amdgcn_rcpf(1.f + __expf(-xe));
    float so_f = xo * __builtin_amdgcn_rcpf(1.f + __expf(-xo));
    unsigned se = f16u(se_f), so = f16u(so_f);

    unsigned long long loE, hiE, loO, hiO;
    spline_window(xe, loE, hiE);
    spline_window(xo, loO, hiO);

    unsigned wv[9];
    wv[0] = se | ((unsigned)loE << 16);
    wv[1] = (unsigned)(loE >> 16);
    wv[2] = (unsigned)(loE >> 48) | ((unsigned)hiE << 16);
    wv[3] = (unsigned)(hiE >> 16);
    wv[4] = (unsigned)(hiE >> 48) | (so << 16);
    wv[5] = (unsigned)loO;
    wv[6] = (unsigned)(loO >> 32);
    wv[7] = (unsigned)hiO;
    wv[8] = (unsigned)(hiO >> 32);

    int base = lbase + 18 * d;   // d even -> 4B aligned
#pragma unroll
    for (int j = 0; j < 9; ++j)
        *(unsigned*)(&lds[(base + 4 * j) ^ Xsw]) = wv[j];
}

// ---------------------------------------------------------------------------
// Fused KANLinear PAIR via f16 MFMA (16x16x32), NTILE=32 (R9-proven geometry,
// 36.9 KB LDS -> 4 blocks/CU). Layer A's output relays through a f16 c1
// buffer OVERLAID on the feat LDS region (feat is dead between MFMA-A's
// reads and featB's writes) — zero extra LDS, unlike R7's +8.3 KB version.
// Sequence: featA | bar | MFMA-A | bar | write c1 | bar | read c1->regs |
// bar | featB | bar | MFMA-B | store. f16 in; f16 (F32OUT=0) or f32 out.
// ---------------------------------------------------------------------------
template<int F32OUT>
__global__ __launch_bounds__(256) void kan2_mfma(const _Float16* __restrict__ xin,
                                                 const uint4* __restrict__ wlA,
                                                 const uint4* __restrict__ wlB,
                                                 void* __restrict__ outp) {
    __shared__ alignas(16) char lds[NTILE * 1152];  // 36864 B
    _Float16* c1 = (_Float16*)lds;                  // overlay [32][C1S]

    int tid = threadIdx.x;
    int lane = tid & 63;
    int w = tid >> 6;
    int node0 = blockIdx.x * NTILE;

    int fn = tid >> 3;
    int fq = tid & 7;
    int Xsw = (fn & 7) << 4;
    int lbase = fn * 1152;
    int row = lane & 15, kg = lane >> 4;
    int xr = (row & 7) << 4;
    int rb0 = row * 1152;
    int rb1 = (16 + row) * 1152;
    int o = w * 16 + row;
    int rbase = kg * 4;

    // ---- featA (from global) ----
    {
        const _Float16* xr_ = &xin[(size_t)(node0 + fn) * DIM + fq * 4];
        f16x4 h0 = *(const f16x4*)(xr_);
        f16x4 h1 = *(const f16x4*)(xr_ + 32);
        int d0 = fq * 4;
        feat_pair(lds, lbase, Xsw, d0,          (float)h0[0], (float)h0[1]);
        feat_pair(lds, lbase, Xsw, d0 + 2,      (float)h0[2], (float)h0[3]);
        feat_pair(lds, lbase, Xsw, d0 + 32,     (float)h1[0], (float)h1[1]);
        feat_pair(lds, lbase, Xsw, d0 + 32 + 2, (float)h1[2], (float)h1[3]);
    }
    __syncthreads();

    // ---- MFMA A ----
    f32x4 acc0 = {0.f, 0.f, 0.f, 0.f};
    f32x4 acc1 = {0.f, 0.f, 0.f, 0.f};
#pragma unroll
    for (int s = 0; s < NSTEP; ++s) {
        f16x8 bh = __builtin_bit_cast(f16x8, wlA[(s * 4 + w) * 64 + lane]);
        int pofs = ((s * 4 + kg) << 4) ^ xr;
        f16x8 a0 = *(const f16x8*)(&lds[rb0 + pofs]);
        f16x8 a1 = *(const f16x8*)(&lds[rb1 + pofs]);
        acc0 = __builtin_amdgcn_mfma_f32_16x16x32_f16(a0, bh, acc0, 0, 0, 0);
        acc1 = __builtin_amdgcn_mfma_f32_16x16x32_f16(a1, bh, acc1, 0, 0, 0);
    }
    __syncthreads();   // all feat reads done; c1 region may be overwritten

    // ---- write c1 (f16, overlaid) ----
#pragma unroll
    for (int r = 0; r < 4; ++r) {
        c1[(rbase + r) * C1S + o]      = (_Float16)acc0[r];
        c1[(16 + rbase + r) * C1S + o] = (_Float16)acc1[r];
    }
    __syncthreads();

    // ---- read c1 to regs (this thread's 8 layer-B inputs) ----
    f16x4 g0 = *(const f16x4*)&c1[fn * C1S + fq * 4];
    f16x4 g1 = *(const f16x4*)&c1[fn * C1S + fq * 4 + 32];
    __syncthreads();   // c1 reads done; feat region free for featB

    // ---- featB ----
    {
        int d0 = fq * 4;
        feat_pair(lds, lbase, Xsw, d0,          (float)g0[0], (float)g0[1]);
        feat_pair(lds, lbase, Xsw, d0 + 2,      (float)g0[2], (float)g0[3]);
        feat_pair(lds, lbase, Xsw, d0 + 32,     (float)g1[0], (float)g1[1]);
        feat_pair(lds, lbase, Xsw, d0 + 32 + 2, (float)g1[2], (float)g1[3]);
    }
    __syncthreads();

    // ---- MFMA B ----
    acc0 = (f32x4){0.f, 0.f, 0.f, 0.f};
    acc1 = (f32x4){0.f, 0.f, 0.f, 0.f};
#pragma unroll
    for (int s = 0; s < NSTEP; ++s) {
        f16x8 bh = __builtin_bit_cast(f16x8, wlB[(s * 4 + w) * 64 + lane]);
        int pofs = ((s * 4 + kg) << 4) ^ xr;
        f16x8 a0 = *(const f16x8*)(&lds[rb0 + pofs]);
        f16x8 a1 = *(const f16x8*)(&lds[rb1 + pofs]);
        acc0 = __builtin_amdgcn_mfma_f32_16x16x32_f16(a0, bh, acc0, 0, 0, 0);
        acc1 = __builtin_amdgcn_mfma_f32_16x16x32_f16(a1, bh, acc1, 0, 0, 0);
    }

    // ---- store: C layout col=lane&15 (o), row=(lane>>4)*4+r (node) ----
    if (F32OUT) {
        float* out = (float*)outp;
#pragma unroll
        for (int r = 0; r < 4; ++r) {
            out[(size_t)(node0 + rbase + r) * DIM + o]      = acc0[r];
            out[(size_t)(node0 + 16 + rbase + r) * DIM + o] = acc1[r];
        }
    } else {
        _Float16* out = (_Float16*)outp;
#pragma unroll
        for (int r = 0; r < 4; ++r) {
            out[(size_t)(node0 + rbase + r) * DIM + o]      = (_Float16)acc0[r];
            out[(size_t)(node0 + 16 + rbase + r) * DIM + o] = (_Float16)acc1[r];
        }
    }
}

extern "C" void kernel_launch(void* const* d_in, const int* in_sizes, int n_in,
                              void* d_out, int out_size, void* d_ws, size_t ws_size,
                              hipStream_t stream) {
    const float* x     = (const float*)d_in[0];
    const float* eval_ = (const float*)d_in[1];
    const float* bw    = (const float*)d_in[2];
    const float* sw    = (const float*)d_in[3];
    const float* ss    = (const float*)d_in[4];
    const int*   erow  = (const int*)d_in[5];
    const int*   ecol  = (const int*)d_in[6];
    float* out = (float*)d_out;

    // ws layout: [H0: 12.8MB f16][H1: 12.8MB f16][wcf: 442368B][rp: 400004B]
    const size_t HB = (size_t)N_NODES * DIM * sizeof(_Float16);
    _Float16* H0 = (_Float16*)d_ws;
    _Float16* H1 = (_Float16*)((char*)d_ws + HB);
    uint4* wcf = (uint4*)((char*)d_ws + 2 * HB);
    int*   rp  = (int*)((char*)d_ws + 2 * HB + 442368);

    const size_t WL = (size_t)NSTEP * 4 * 64;  // uint4 per layer

    prep<<<WCF_BLOCKS + RP_BLOCKS + CONV_BLOCKS, 256, 0, stream>>>(
        bw, sw, ss, wcf, erow, rp, x, H0);

    const int SPMM_BLOCKS = N_NODES / 4;

    spmm_kernel<<<SPMM_BLOCKS, 256, 0, stream>>>(rp, ecol, eval_, H0, H1);
    kan2_mfma<0><<<KAN_BLOCKS, 256, 0, stream>>>(H1, wcf + 0 * WL, wcf + 1 * WL, H0);

    spmm_kernel<<<SPMM_BLOCKS, 256, 0, stream>>>(rp, ecol, eval_, H0, H1);
    kan2_mfma<0><<<KAN_BLOCKS, 256, 0, stream>>>(H1, wcf + 2 * WL, wcf + 3 * WL, H0);

    spmm_kernel<<<SPMM_BLOCKS, 256, 0, stream>>>(rp, ecol, eval_, H0, H1);
    kan2_mfma<1><<<KAN_BLOCKS, 256, 0, stream>>>(H1, wcf + 4 * WL, wcf + 5 * WL, out);
}